// Round 8
// baseline (1619.968 us; speedup 1.0000x reference)
//
#include <hip/hip_runtime.h>

#define N_NODES 50000
#define E_EDGES 200000
#define ET_EDGES (E_EDGES + N_NODES)
#define G_GRAPHS 2000
#define F_IN 64
#define HID 128
#define HEADS 4
#define DM 512
#define BN_EPS 1e-5f
#define NEG_SLOPE 0.2f

typedef unsigned short ushort_t;
typedef float floatx4 __attribute__((ext_vector_type(4)));
typedef short short8 __attribute__((ext_vector_type(8)));

__device__ __forceinline__ float b2f(unsigned int u) {
    union { unsigned int i; float f; } v; v.i = u << 16; return v.f;
}
__device__ __forceinline__ ushort_t f2b(float f) {
    union { float f; unsigned int i; } v; v.f = f;
    unsigned int r = v.i + 0x7FFFu + ((v.i >> 16) & 1u);   // RNE
    return (ushort_t)(r >> 16);
}
// split f32 into bf16 hi + bf16 lo:  x ≈ hi + lo, |err| <= 2^-18 |x|
__device__ __forceinline__ void split_bf(float x, ushort_t& h, ushort_t& l) {
    h = f2b(x);
    l = f2b(x - b2f(h));
}

// ---------- W[K,512] f32 -> Wt_hi/Wt_lo [512,K] bf16 (transpose + split) ----------
__global__ __launch_bounds__(256) void k_wprep(const float* __restrict__ W,
                                               ushort_t* __restrict__ Wh,
                                               ushort_t* __restrict__ Wl, int K) {
    int t = blockIdx.x * 256 + threadIdx.x;
    if (t >= K * DM) return;
    int k = t >> 9, n = t & 511;            // t = k*512 + n (coalesced read)
    ushort_t h, l; split_bf(W[t], h, l);
    Wh[(size_t)n * K + k] = h;
    Wl[(size_t)n * K + k] = l;
}

// ---------- MFMA GEMM, f32-faithful, fused BN-on-input + attention scores ----------
// C[M,512] = f(A)[M,K] @ W[K,512], f(a)=max(a*bnsc+bnsh,0) if bnsc else a.
// Each block's 128 output cols = exactly one head -> ssrc/sdst computed in epilogue.
#define LDST 40   // 32 + 8 pad (bf16 elems), 80B rows
__global__ __launch_bounds__(256) void k_mgemm(const float* __restrict__ A,
                                               const ushort_t* __restrict__ Bh,
                                               const ushort_t* __restrict__ Bl,
                                               const float* __restrict__ bnsc,
                                               const float* __restrict__ bnsh,
                                               const float* __restrict__ a_s,
                                               const float* __restrict__ a_d,
                                               float* __restrict__ C,
                                               float* __restrict__ ssrc,
                                               float* __restrict__ sdst,
                                               int M, int K) {
    __shared__ __align__(16) ushort_t Ash[128 * LDST];
    __shared__ __align__(16) ushort_t Asl[128 * LDST];
    __shared__ __align__(16) ushort_t Bsh[128 * LDST];
    __shared__ __align__(16) ushort_t Bsl[128 * LDST];
    __shared__ float sS[128], sD[128];
    int tid = threadIdx.x;
    int lane = tid & 63, wave = tid >> 6;
    int m0 = blockIdx.y * 128, n0 = blockIdx.x * 128;
    int wm = (wave >> 1) * 64, wn = (wave & 1) * 64;
    int r0 = tid >> 2, kv = tid & 3;
    floatx4 acc[4][4] = {};
    int rA1 = m0 + r0;      if (rA1 >= M) rA1 = M - 1;
    int rA2 = m0 + r0 + 64; if (rA2 >= M) rA2 = M - 1;
    const float* pa1 = A + (size_t)rA1 * K + kv * 8;
    const float* pa2 = A + (size_t)rA2 * K + kv * 8;
    const ushort_t* pbh1 = Bh + (size_t)(n0 + r0) * K + kv * 8;
    const ushort_t* pbh2 = Bh + (size_t)(n0 + r0 + 64) * K + kv * 8;
    const ushort_t* pbl1 = Bl + (size_t)(n0 + r0) * K + kv * 8;
    const ushort_t* pbl2 = Bl + (size_t)(n0 + r0 + 64) * K + kv * 8;
    int rF = lane & 15, kq = (lane >> 4) * 8;
    if (tid < 128) { sS[tid] = 0.f; sD[tid] = 0.f; }
    for (int k0 = 0; k0 < K; k0 += 32) {
        float4 a1a = *(const float4*)(pa1 + k0);
        float4 a1b = *(const float4*)(pa1 + k0 + 4);
        float4 a2a = *(const float4*)(pa2 + k0);
        float4 a2b = *(const float4*)(pa2 + k0 + 4);
        uint4 b1h = *(const uint4*)(pbh1 + k0);
        uint4 b2h = *(const uint4*)(pbh2 + k0);
        uint4 b1l = *(const uint4*)(pbl1 + k0);
        uint4 b2l = *(const uint4*)(pbl2 + k0);
        float v1[8] = { a1a.x, a1a.y, a1a.z, a1a.w, a1b.x, a1b.y, a1b.z, a1b.w };
        float v2[8] = { a2a.x, a2a.y, a2a.z, a2a.w, a2b.x, a2b.y, a2b.z, a2b.w };
        if (bnsc) {   // fused BN-apply + ReLU on the input features
            const float* sp = bnsc + k0 + kv * 8;
            const float* tp = bnsh + k0 + kv * 8;
#pragma unroll
            for (int j = 0; j < 8; ++j) {
                float sj = sp[j], tj = tp[j];
                v1[j] = fmaxf(v1[j] * sj + tj, 0.f);
                v2[j] = fmaxf(v2[j] * sj + tj, 0.f);
            }
        }
        uint4 a1h, a1l, a2h, a2l;
        unsigned* p1h = (unsigned*)&a1h; unsigned* p1l = (unsigned*)&a1l;
        unsigned* p2h = (unsigned*)&a2h; unsigned* p2l = (unsigned*)&a2l;
#pragma unroll
        for (int j = 0; j < 4; ++j) {
            ushort_t h0, l0, h1, l1;
            split_bf(v1[2 * j], h0, l0); split_bf(v1[2 * j + 1], h1, l1);
            p1h[j] = (unsigned)h0 | ((unsigned)h1 << 16);
            p1l[j] = (unsigned)l0 | ((unsigned)l1 << 16);
            split_bf(v2[2 * j], h0, l0); split_bf(v2[2 * j + 1], h1, l1);
            p2h[j] = (unsigned)h0 | ((unsigned)h1 << 16);
            p2l[j] = (unsigned)l0 | ((unsigned)l1 << 16);
        }
        __syncthreads();
        *(uint4*)&Ash[r0 * LDST + kv * 8] = a1h;
        *(uint4*)&Asl[r0 * LDST + kv * 8] = a1l;
        *(uint4*)&Ash[(r0 + 64) * LDST + kv * 8] = a2h;
        *(uint4*)&Asl[(r0 + 64) * LDST + kv * 8] = a2l;
        *(uint4*)&Bsh[r0 * LDST + kv * 8] = b1h;
        *(uint4*)&Bsl[r0 * LDST + kv * 8] = b1l;
        *(uint4*)&Bsh[(r0 + 64) * LDST + kv * 8] = b2h;
        *(uint4*)&Bsl[(r0 + 64) * LDST + kv * 8] = b2l;
        __syncthreads();
        short8 afh[4], afl[4], bfh[4], bfl[4];
#pragma unroll
        for (int i = 0; i < 4; ++i) {
            afh[i] = *(const short8*)&Ash[(wm + i * 16 + rF) * LDST + kq];
            afl[i] = *(const short8*)&Asl[(wm + i * 16 + rF) * LDST + kq];
        }
#pragma unroll
        for (int j = 0; j < 4; ++j) {
            bfh[j] = *(const short8*)&Bsh[(wn + j * 16 + rF) * LDST + kq];
            bfl[j] = *(const short8*)&Bsl[(wn + j * 16 + rF) * LDST + kq];
        }
#pragma unroll
        for (int i = 0; i < 4; ++i)
#pragma unroll
            for (int j = 0; j < 4; ++j) {
                acc[i][j] = __builtin_amdgcn_mfma_f32_16x16x32_bf16(afh[i], bfh[j], acc[i][j], 0, 0, 0);
                acc[i][j] = __builtin_amdgcn_mfma_f32_16x16x32_bf16(afl[i], bfh[j], acc[i][j], 0, 0, 0);
                acc[i][j] = __builtin_amdgcn_mfma_f32_16x16x32_bf16(afh[i], bfl[j], acc[i][j], 0, 0, 0);
            }
    }
    // C/D layout: col=lane&15, row=(lane>>4)*4+reg   [m89-verified]
    int cr = (lane >> 4) * 4, cc = lane & 15;
#pragma unroll
    for (int i = 0; i < 4; ++i) {
#pragma unroll
        for (int r = 0; r < 4; ++r) {
            int gr = m0 + wm + i * 16 + cr + r;
            if (gr < M) {
#pragma unroll
                for (int j = 0; j < 4; ++j)
                    C[(size_t)gr * DM + n0 + wn + j * 16 + cc] = acc[i][j][r];
            }
        }
    }
    // ---- fused attention scores: this block's 128 cols == head blockIdx.x ----
    int head = blockIdx.x;
    float asl_[4], adl_[4];
#pragma unroll
    for (int j = 0; j < 4; ++j) {
        int c = wn + j * 16 + cc;
        asl_[j] = a_s[head * HID + c];
        adl_[j] = a_d[head * HID + c];
    }
#pragma unroll
    for (int i = 0; i < 4; ++i) {
#pragma unroll
        for (int r = 0; r < 4; ++r) {
            float ps = 0.f, pd = 0.f;
#pragma unroll
            for (int j = 0; j < 4; ++j) {
                ps += acc[i][j][r] * asl_[j];
                pd += acc[i][j][r] * adl_[j];
            }
#pragma unroll
            for (int mk = 1; mk < 16; mk <<= 1) {
                ps += __shfl_xor(ps, mk);
                pd += __shfl_xor(pd, mk);
            }
            if (cc == 0) {
                int row = wm + i * 16 + (lane >> 4) * 4 + r;
                atomicAdd(&sS[row], ps);
                atomicAdd(&sD[row], pd);
            }
        }
    }
    __syncthreads();
    if (tid < 128) {
        int gr = m0 + tid;
        if (gr < M) {
            ssrc[gr * 4 + head] = sS[tid];
            sdst[gr * 4 + head] = sD[tid];
        }
    }
}

// ---------- CSR build ----------
__global__ void k_degree(const int* __restrict__ ei, int* __restrict__ deg) {
    int e = blockIdx.x * blockDim.x + threadIdx.x;
    if (e >= ET_EDGES) return;
    int d = (e < E_EDGES) ? ei[E_EDGES + e] : (e - E_EDGES);
    atomicAdd(&deg[d], 1);
}

__global__ __launch_bounds__(1024) void k_scan2(const int* __restrict__ deg,
                                                int* __restrict__ offs) {
    __shared__ int part[1025];
    int t = threadIdx.x;
    const int CH = (N_NODES + 1023) / 1024;
    int lo = t * CH, hi = lo + CH; if (hi > N_NODES) hi = N_NODES; if (lo > N_NODES) lo = N_NODES;
    int s = 0;
    for (int i = lo; i < hi; ++i) s += deg[i];
    part[t] = s;
    __syncthreads();
    if (t == 0) {
        int acc = 0;
        for (int i = 0; i < 1024; ++i) { int v = part[i]; part[i] = acc; acc += v; }
        part[1024] = acc;
    }
    __syncthreads();
    int acc = part[t];
    for (int i = lo; i < hi; ++i) { offs[i] = acc; acc += deg[i]; }
    if (t == 1023) offs[N_NODES] = part[1024];
}

__global__ void k_scatter(const int* __restrict__ ei, int* __restrict__ cursor,
                          int* __restrict__ csr_src) {
    int e = blockIdx.x * blockDim.x + threadIdx.x;
    if (e >= ET_EDGES) return;
    int sv, d;
    if (e < E_EDGES) { sv = ei[e]; d = ei[E_EDGES + e]; } else { sv = d = e - E_EDGES; }
    int pos = atomicAdd(&cursor[d], 1);
    csr_src[pos] = sv;
}

__global__ void k_gbounds(const int* __restrict__ batch, int* __restrict__ gstart) {
    int i = blockIdx.x * blockDim.x + threadIdx.x;
    if (i >= N_NODES) return;
    int b = batch[i];
    int p = (i == 0) ? -1 : batch[i - 1];
    for (int g = p + 1; g <= b; ++g) gstart[g] = i;
    if (i == N_NODES - 1)
        for (int g = b + 1; g <= G_GRAPHS; ++g) gstart[g] = N_NODES;
}

// ---------- softmax max & denom per (node,head): single-pass online ----------
__global__ __launch_bounds__(256) void k_msum(const float* __restrict__ ssrc,
                                              const float* __restrict__ sdst,
                                              const int* __restrict__ offs,
                                              const int* __restrict__ csr_src,
                                              float* __restrict__ msum,
                                              float* __restrict__ ssum) {
    int t = blockIdx.x * 256 + threadIdx.x;
    if (t >= N_NODES * HEADS) return;
    int n = t >> 2, h = t & 3;
    int beg = offs[n], end = offs[n + 1];
    float sdh = sdst[n * 4 + h];
    float m = -1e30f, s = 0.f;
    for (int e = beg; e < end; ++e) {
        float sc = ssrc[csr_src[e] * 4 + h] + sdh;
        sc = sc > 0.f ? sc : NEG_SLOPE * sc;
        if (sc > m) { s = s * __expf(m - sc) + 1.f; m = sc; }
        else s += __expf(sc - m);
    }
    msum[t] = m; ssum[t] = s;
}

// ---------- GAT aggregate: one wave per dst node, 4-edge pipelined ----------
__global__ __launch_bounds__(256) void k_aggregate(const float* __restrict__ H,
                                                   const float* __restrict__ ssrc,
                                                   const float* __restrict__ sdst,
                                                   const float* __restrict__ msum,
                                                   const float* __restrict__ ssum,
                                                   const int* __restrict__ offs,
                                                   const int* __restrict__ csr_src,
                                                   const float* __restrict__ bias,
                                                   float* __restrict__ out) {
    int wave = threadIdx.x >> 6, lane = threadIdx.x & 63;
    int n = blockIdx.x * 4 + wave;
    if (n >= N_NODES) return;
    int beg = offs[n], end = offs[n + 1];
    int hl = lane >> 4;                       // lane's 8 features all in head lane>>4
    float sdh = sdst[n * 4 + hl];
    float mh = msum[n * 4 + hl];
    float inv = 1.f / ssum[n * 4 + hl];
    float acc[8] = { 0.f, 0.f, 0.f, 0.f, 0.f, 0.f, 0.f, 0.f };
    int e = beg;
    for (; e + 4 <= end; e += 4) {
        int sv0 = csr_src[e], sv1 = csr_src[e + 1];
        int sv2 = csr_src[e + 2], sv3 = csr_src[e + 3];
        float s0 = ssrc[sv0 * 4 + hl], s1 = ssrc[sv1 * 4 + hl];
        float s2 = ssrc[sv2 * 4 + hl], s3 = ssrc[sv3 * 4 + hl];
        const float* hp0 = H + (size_t)sv0 * DM + lane * 8;
        const float* hp1 = H + (size_t)sv1 * DM + lane * 8;
        const float* hp2 = H + (size_t)sv2 * DM + lane * 8;
        const float* hp3 = H + (size_t)sv3 * DM + lane * 8;
        float4 h0a = *(const float4*)hp0, h0b = *(const float4*)(hp0 + 4);
        float4 h1a = *(const float4*)hp1, h1b = *(const float4*)(hp1 + 4);
        float4 h2a = *(const float4*)hp2, h2b = *(const float4*)(hp2 + 4);
        float4 h3a = *(const float4*)hp3, h3b = *(const float4*)(hp3 + 4);
        s0 += sdh; s0 = s0 > 0.f ? s0 : NEG_SLOPE * s0;
        s1 += sdh; s1 = s1 > 0.f ? s1 : NEG_SLOPE * s1;
        s2 += sdh; s2 = s2 > 0.f ? s2 : NEG_SLOPE * s2;
        s3 += sdh; s3 = s3 > 0.f ? s3 : NEG_SLOPE * s3;
        float a0 = __expf(s0 - mh) * inv, a1 = __expf(s1 - mh) * inv;
        float a2 = __expf(s2 - mh) * inv, a3 = __expf(s3 - mh) * inv;
        acc[0] += a0 * h0a.x + a1 * h1a.x + a2 * h2a.x + a3 * h3a.x;
        acc[1] += a0 * h0a.y + a1 * h1a.y + a2 * h2a.y + a3 * h3a.y;
        acc[2] += a0 * h0a.z + a1 * h1a.z + a2 * h2a.z + a3 * h3a.z;
        acc[3] += a0 * h0a.w + a1 * h1a.w + a2 * h2a.w + a3 * h3a.w;
        acc[4] += a0 * h0b.x + a1 * h1b.x + a2 * h2b.x + a3 * h3b.x;
        acc[5] += a0 * h0b.y + a1 * h1b.y + a2 * h2b.y + a3 * h3b.y;
        acc[6] += a0 * h0b.z + a1 * h1b.z + a2 * h2b.z + a3 * h3b.z;
        acc[7] += a0 * h0b.w + a1 * h1b.w + a2 * h2b.w + a3 * h3b.w;
    }
    for (; e < end; ++e) {
        int sv = csr_src[e];
        float sc = ssrc[sv * 4 + hl] + sdh;
        sc = sc > 0.f ? sc : NEG_SLOPE * sc;
        float alpha = __expf(sc - mh) * inv;
        const float* hp = H + (size_t)sv * DM + lane * 8;
        float4 h0 = *(const float4*)hp;
        float4 h1 = *(const float4*)(hp + 4);
        acc[0] += alpha * h0.x; acc[1] += alpha * h0.y;
        acc[2] += alpha * h0.z; acc[3] += alpha * h0.w;
        acc[4] += alpha * h1.x; acc[5] += alpha * h1.y;
        acc[6] += alpha * h1.z; acc[7] += alpha * h1.w;
    }
    const float* bp = bias + lane * 8;
    float4 b0 = *(const float4*)bp;
    float4 b1 = *(const float4*)(bp + 4);
    float* op = out + (size_t)n * DM + lane * 8;
    float4 o0, o1;
    o0.x = acc[0] + b0.x; o0.y = acc[1] + b0.y; o0.z = acc[2] + b0.z; o0.w = acc[3] + b0.w;
    o1.x = acc[4] + b1.x; o1.y = acc[5] + b1.y; o1.z = acc[6] + b1.z; o1.w = acc[7] + b1.w;
    *(float4*)op = o0;
    *(float4*)(op + 4) = o1;
}

// ---------- BatchNorm stats / finalize ----------
__global__ __launch_bounds__(256) void k_bnstats(const float* __restrict__ X,
                                                 float* __restrict__ stat) {
    int t = threadIdx.x;
    int c = t & 63, r = t >> 6;
    float sum[8] = { 0 }, sq[8] = { 0 };
    for (int n = blockIdx.x * 4 + r; n < N_NODES; n += gridDim.x * 4) {
        const float* xp = X + (size_t)n * DM + c * 8;
        float4 x0 = *(const float4*)xp;
        float4 x1 = *(const float4*)(xp + 4);
        float f[8] = { x0.x, x0.y, x0.z, x0.w, x1.x, x1.y, x1.z, x1.w };
#pragma unroll
        for (int j = 0; j < 8; ++j) { sum[j] += f[j]; sq[j] += f[j] * f[j]; }
    }
#pragma unroll
    for (int j = 0; j < 8; ++j) {
        atomicAdd(&stat[c * 8 + j], sum[j]);
        atomicAdd(&stat[512 + c * 8 + j], sq[j]);
    }
}

__global__ void k_bnfin(const float* __restrict__ stat, const float* __restrict__ g,
                        const float* __restrict__ be, float* __restrict__ scale,
                        float* __restrict__ shift) {
    int f = blockIdx.x * blockDim.x + threadIdx.x;
    if (f >= DM) return;
    float mu = stat[f] * (1.f / (float)N_NODES);
    float var = stat[512 + f] * (1.f / (float)N_NODES) - mu * mu;
    var = fmaxf(var, 0.f);
    float rs = rsqrtf(var + BN_EPS);
    float sc = g[f] * rs;
    scale[f] = sc;
    shift[f] = be[f] - mu * sc;
}

// ---------- graph pooling, fused final BN+ReLU: one wave per graph ----------
__global__ __launch_bounds__(64) void k_pool(const float* __restrict__ X,
                                             const int* __restrict__ gstart,
                                             const float* __restrict__ bnsc,
                                             const float* __restrict__ bnsh,
                                             float* __restrict__ pool) {
    int g = blockIdx.x, t = threadIdx.x;   // 64 threads, 8 feats each
    int beg = gstart[g], end = gstart[g + 1];
    const float* sp = bnsc + t * 8;
    const float* tp = bnsh + t * 8;
    float sc[8], sh[8];
#pragma unroll
    for (int j = 0; j < 8; ++j) { sc[j] = sp[j]; sh[j] = tp[j]; }
    float sum[8] = { 0 }, mx[8];
#pragma unroll
    for (int j = 0; j < 8; ++j) mx[j] = -1e30f;
    for (int nn = beg; nn < end; ++nn) {
        const float* xp = X + (size_t)nn * DM + t * 8;
        float4 x0 = *(const float4*)xp;
        float4 x1 = *(const float4*)(xp + 4);
        float f[8] = { x0.x, x0.y, x0.z, x0.w, x1.x, x1.y, x1.z, x1.w };
#pragma unroll
        for (int j = 0; j < 8; ++j) {
            f[j] = fmaxf(f[j] * sc[j] + sh[j], 0.f);
            sum[j] += f[j]; mx[j] = fmaxf(mx[j], f[j]);
        }
    }
    float cnt = (float)(end - beg);
    float inv = cnt > 0.f ? 1.f / cnt : 0.f;
#pragma unroll
    for (int j = 0; j < 8; ++j) {
        pool[(size_t)g * 1024 + t * 8 + j] = sum[j] * inv;
        pool[(size_t)g * 1024 + 512 + t * 8 + j] = cnt > 0.f ? mx[j] : 0.f;
    }
}

// ---------- MLP head: one block per graph; f32 throughout ----------
__global__ __launch_bounds__(128) void k_mlp(const float* __restrict__ pool,
                                             const float* __restrict__ c1w,
                                             const float* __restrict__ c1b,
                                             const float* __restrict__ c2w,
                                             const float* __restrict__ c2b,
                                             const float* __restrict__ c3w,
                                             const float* __restrict__ c3b,
                                             float* __restrict__ out) {
    __shared__ float row[1024];
    __shared__ float h1[128];
    __shared__ float h2[64];
    int g = blockIdx.x, t = threadIdx.x;
    for (int i = t; i < 1024; i += 128) row[i] = pool[(size_t)g * 1024 + i];
    __syncthreads();
    float a1 = c1b[t];
#pragma unroll 8
    for (int k = 0; k < 1024; ++k) a1 += row[k] * c1w[k * 128 + t];
    h1[t] = fmaxf(a1, 0.f);
    __syncthreads();
    if (t < 64) {
        float a2 = c2b[t];
#pragma unroll 8
        for (int k = 0; k < 128; ++k) a2 += h1[k] * c2w[k * 64 + t];
        h2[t] = fmaxf(a2, 0.f);
    }
    __syncthreads();
    if (t < 64) {
        float p = h2[t] * c3w[t];
#pragma unroll
        for (int off = 32; off > 0; off >>= 1) p += __shfl_down(p, off);
        if (t == 0) {
            float z = p + c3b[0];
            out[g] = 1.f / (1.f + __expf(-z));      // float32 output
        }
    }
}

extern "C" void kernel_launch(void* const* d_in, const int* in_sizes, int n_in,
                              void* d_out, int out_size, void* d_ws, size_t ws_size,
                              hipStream_t stream) {
    const float* x = (const float*)d_in[0];
    const int* ei = (const int*)d_in[1];
    const int* batch = (const int*)d_in[2];
    const float* c1w = (const float*)d_in[21];
    const float* c1b = (const float*)d_in[22];
    const float* c2w = (const float*)d_in[23];
    const float* c2b = (const float*)d_in[24];
    const float* c3w = (const float*)d_in[25];
    const float* c3b = (const float*)d_in[26];

    char* p = (char*)d_ws;
    auto carve = [&](size_t bytes) -> char* {
        char* r = p; p += (bytes + 255) & ~(size_t)255; return r;
    };
    float*    A      = (float*)carve((size_t)N_NODES * DM * 4);   // aggregate output (pre-BN)
    float*    Hb     = (float*)carve((size_t)N_NODES * DM * 4);   // h = f(x)@W
    ushort_t* Wh     = (ushort_t*)carve((size_t)DM * DM * 2);     // W^T hi (bf16)
    ushort_t* Wl     = (ushort_t*)carve((size_t)DM * DM * 2);     // W^T lo (bf16)
    float*    ssrc   = (float*)carve((size_t)N_NODES * 4 * 4);
    float*    sdst   = (float*)carve((size_t)N_NODES * 4 * 4);
    float*    msum   = (float*)carve((size_t)N_NODES * 4 * 4);
    float*    ssum   = (float*)carve((size_t)N_NODES * 4 * 4);
    int*      deg    = (int*)carve((size_t)N_NODES * 4);
    int*      offs   = (int*)carve((size_t)(N_NODES + 1) * 4);
    int*      cursor = (int*)carve((size_t)N_NODES * 4);
    int*      csrsrc = (int*)carve((size_t)ET_EDGES * 4);
    float*    bnstat = (float*)carve(1024 * 4);
    float*    bnscale= (float*)carve(512 * 4);
    float*    bnshift= (float*)carve(512 * 4);
    int*      gstart = (int*)carve((size_t)(G_GRAPHS + 1) * 4);
    float*    pool   = (float*)carve((size_t)G_GRAPHS * 1024 * 4);

    // --- CSR by dst (self-loops appended) + graph bounds ---
    hipMemsetAsync(deg, 0, (size_t)N_NODES * 4, stream);
    k_degree<<<(ET_EDGES + 255) / 256, 256, 0, stream>>>(ei, deg);
    k_scan2<<<1, 1024, 0, stream>>>(deg, offs);
    hipMemcpyAsync(cursor, offs, (size_t)N_NODES * 4, hipMemcpyDeviceToDevice, stream);
    k_scatter<<<(ET_EDGES + 255) / 256, 256, 0, stream>>>(ei, cursor, csrsrc);
    k_gbounds<<<(N_NODES + 255) / 256, 256, 0, stream>>>(batch, gstart);

    const float* xin = x;
    const float* bns = nullptr;   // BN scale/shift applied to mgemm input (fused)
    const float* bnh = nullptr;
    for (int l = 0; l < 3; ++l) {
        int K = (l == 0) ? F_IN : DM;
        const float* W   = (const float*)d_in[3 + 6 * l];
        const float* as_ = (const float*)d_in[4 + 6 * l];
        const float* ad_ = (const float*)d_in[5 + 6 * l];
        const float* bia = (const float*)d_in[6 + 6 * l];
        const float* gam = (const float*)d_in[7 + 6 * l];
        const float* bet = (const float*)d_in[8 + 6 * l];

        k_wprep<<<(K * DM + 255) / 256, 256, 0, stream>>>(W, Wh, Wl, K);
        k_mgemm<<<dim3(4, (N_NODES + 127) / 128), 256, 0, stream>>>(
            xin, Wh, Wl, bns, bnh, as_, ad_, Hb, ssrc, sdst, N_NODES, K);
        k_msum<<<(N_NODES * HEADS + 255) / 256, 256, 0, stream>>>(ssrc, sdst, offs, csrsrc, msum, ssum);
        k_aggregate<<<(N_NODES + 3) / 4, 256, 0, stream>>>(Hb, ssrc, sdst, msum, ssum, offs, csrsrc, bia, A);
        hipMemsetAsync(bnstat, 0, 1024 * 4, stream);
        k_bnstats<<<304, 256, 0, stream>>>(A, bnstat);
        k_bnfin<<<2, 256, 0, stream>>>(bnstat, gam, bet, bnscale, bnshift);
        xin = A; bns = bnscale; bnh = bnshift;
    }
    k_pool<<<G_GRAPHS, 64, 0, stream>>>(A, gstart, bnscale, bnshift, pool);
    k_mlp<<<G_GRAPHS, 128, 0, stream>>>(pool, c1w, c1b, c2w, c2b, c3w, c3b,
                                        (float*)d_out);
}

// Round 9
// 1032.836 us; speedup vs baseline: 1.5685x; 1.5685x over previous
//
#include <hip/hip_runtime.h>

#define N_NODES 50000
#define E_EDGES 200000
#define ET_EDGES (E_EDGES + N_NODES)
#define G_GRAPHS 2000
#define F_IN 64
#define HID 128
#define HEADS 4
#define DM 512
#define BN_EPS 1e-5f
#define NEG_SLOPE 0.2f

typedef unsigned short ushort_t;
typedef float floatx4 __attribute__((ext_vector_type(4)));
typedef short short8 __attribute__((ext_vector_type(8)));

__device__ __forceinline__ float b2f(unsigned int u) {
    union { unsigned int i; float f; } v; v.i = u << 16; return v.f;
}
__device__ __forceinline__ ushort_t f2b(float f) {
    union { float f; unsigned int i; } v; v.f = f;
    unsigned int r = v.i + 0x7FFFu + ((v.i >> 16) & 1u);   // RNE
    return (ushort_t)(r >> 16);
}
// split f32 into bf16 hi + bf16 lo:  x ≈ hi + lo, |err| <= 2^-18 |x|
__device__ __forceinline__ void split_bf(float x, ushort_t& h, ushort_t& l) {
    h = f2b(x);
    l = f2b(x - b2f(h));
}

// ---------- W[K,512] f32 -> Wt_hi/Wt_lo [512,K] bf16 (transpose + split) ----------
__global__ __launch_bounds__(256) void k_wprep(const float* __restrict__ W,
                                               ushort_t* __restrict__ Wh,
                                               ushort_t* __restrict__ Wl, int K) {
    int t = blockIdx.x * 256 + threadIdx.x;
    if (t >= K * DM) return;
    int k = t >> 9, n = t & 511;            // t = k*512 + n (coalesced read)
    ushort_t h, l; split_bf(W[t], h, l);
    Wh[(size_t)n * K + k] = h;
    Wl[(size_t)n * K + k] = l;
}

// ---------- MFMA GEMM, f32-faithful, fused BN-on-input + attention scores ----------
// C[M,512] = f(A)[M,K] @ W[K,512], f(a)=max(a*bnsc+bnsh,0) if bnsc else a.
// Each block's 128 output cols = exactly one head -> ssrc/sdst computed in epilogue.
#define LDST 40   // 32 + 8 pad (bf16 elems), 80B rows
__global__ __launch_bounds__(256) void k_mgemm(const float* __restrict__ A,
                                               const ushort_t* __restrict__ Bh,
                                               const ushort_t* __restrict__ Bl,
                                               const float* __restrict__ bnsc,
                                               const float* __restrict__ bnsh,
                                               const float* __restrict__ a_s,
                                               const float* __restrict__ a_d,
                                               float* __restrict__ C,
                                               float* __restrict__ ssrc,
                                               float* __restrict__ sdst,
                                               int M, int K) {
    __shared__ __align__(16) ushort_t Ash[128 * LDST];
    __shared__ __align__(16) ushort_t Asl[128 * LDST];
    __shared__ __align__(16) ushort_t Bsh[128 * LDST];
    __shared__ __align__(16) ushort_t Bsl[128 * LDST];
    __shared__ float sS[128], sD[128];
    int tid = threadIdx.x;
    int lane = tid & 63, wave = tid >> 6;
    int m0 = blockIdx.y * 128, n0 = blockIdx.x * 128;
    int wm = (wave >> 1) * 64, wn = (wave & 1) * 64;
    int r0 = tid >> 2, kv = tid & 3;
    floatx4 acc[4][4] = {};
    int rA1 = m0 + r0;      if (rA1 >= M) rA1 = M - 1;
    int rA2 = m0 + r0 + 64; if (rA2 >= M) rA2 = M - 1;
    const float* pa1 = A + (size_t)rA1 * K + kv * 8;
    const float* pa2 = A + (size_t)rA2 * K + kv * 8;
    const ushort_t* pbh1 = Bh + (size_t)(n0 + r0) * K + kv * 8;
    const ushort_t* pbh2 = Bh + (size_t)(n0 + r0 + 64) * K + kv * 8;
    const ushort_t* pbl1 = Bl + (size_t)(n0 + r0) * K + kv * 8;
    const ushort_t* pbl2 = Bl + (size_t)(n0 + r0 + 64) * K + kv * 8;
    int rF = lane & 15, kq = (lane >> 4) * 8;
    if (tid < 128) { sS[tid] = 0.f; sD[tid] = 0.f; }
    for (int k0 = 0; k0 < K; k0 += 32) {
        float4 a1a = *(const float4*)(pa1 + k0);
        float4 a1b = *(const float4*)(pa1 + k0 + 4);
        float4 a2a = *(const float4*)(pa2 + k0);
        float4 a2b = *(const float4*)(pa2 + k0 + 4);
        uint4 b1h = *(const uint4*)(pbh1 + k0);
        uint4 b2h = *(const uint4*)(pbh2 + k0);
        uint4 b1l = *(const uint4*)(pbl1 + k0);
        uint4 b2l = *(const uint4*)(pbl2 + k0);
        float v1[8] = { a1a.x, a1a.y, a1a.z, a1a.w, a1b.x, a1b.y, a1b.z, a1b.w };
        float v2[8] = { a2a.x, a2a.y, a2a.z, a2a.w, a2b.x, a2b.y, a2b.z, a2b.w };
        if (bnsc) {   // fused BN-apply + ReLU on the input features
            const float* sp = bnsc + k0 + kv * 8;
            const float* tp = bnsh + k0 + kv * 8;
#pragma unroll
            for (int j = 0; j < 8; ++j) {
                float sj = sp[j], tj = tp[j];
                v1[j] = fmaxf(v1[j] * sj + tj, 0.f);
                v2[j] = fmaxf(v2[j] * sj + tj, 0.f);
            }
        }
        uint4 a1h, a1l, a2h, a2l;
        unsigned* p1h = (unsigned*)&a1h; unsigned* p1l = (unsigned*)&a1l;
        unsigned* p2h = (unsigned*)&a2h; unsigned* p2l = (unsigned*)&a2l;
#pragma unroll
        for (int j = 0; j < 4; ++j) {
            ushort_t h0, l0, h1, l1;
            split_bf(v1[2 * j], h0, l0); split_bf(v1[2 * j + 1], h1, l1);
            p1h[j] = (unsigned)h0 | ((unsigned)h1 << 16);
            p1l[j] = (unsigned)l0 | ((unsigned)l1 << 16);
            split_bf(v2[2 * j], h0, l0); split_bf(v2[2 * j + 1], h1, l1);
            p2h[j] = (unsigned)h0 | ((unsigned)h1 << 16);
            p2l[j] = (unsigned)l0 | ((unsigned)l1 << 16);
        }
        __syncthreads();
        *(uint4*)&Ash[r0 * LDST + kv * 8] = a1h;
        *(uint4*)&Asl[r0 * LDST + kv * 8] = a1l;
        *(uint4*)&Ash[(r0 + 64) * LDST + kv * 8] = a2h;
        *(uint4*)&Asl[(r0 + 64) * LDST + kv * 8] = a2l;
        *(uint4*)&Bsh[r0 * LDST + kv * 8] = b1h;
        *(uint4*)&Bsl[r0 * LDST + kv * 8] = b1l;
        *(uint4*)&Bsh[(r0 + 64) * LDST + kv * 8] = b2h;
        *(uint4*)&Bsl[(r0 + 64) * LDST + kv * 8] = b2l;
        __syncthreads();
        short8 afh[4], afl[4], bfh[4], bfl[4];
#pragma unroll
        for (int i = 0; i < 4; ++i) {
            afh[i] = *(const short8*)&Ash[(wm + i * 16 + rF) * LDST + kq];
            afl[i] = *(const short8*)&Asl[(wm + i * 16 + rF) * LDST + kq];
        }
#pragma unroll
        for (int j = 0; j < 4; ++j) {
            bfh[j] = *(const short8*)&Bsh[(wn + j * 16 + rF) * LDST + kq];
            bfl[j] = *(const short8*)&Bsl[(wn + j * 16 + rF) * LDST + kq];
        }
#pragma unroll
        for (int i = 0; i < 4; ++i)
#pragma unroll
            for (int j = 0; j < 4; ++j) {
                acc[i][j] = __builtin_amdgcn_mfma_f32_16x16x32_bf16(afh[i], bfh[j], acc[i][j], 0, 0, 0);
                acc[i][j] = __builtin_amdgcn_mfma_f32_16x16x32_bf16(afl[i], bfh[j], acc[i][j], 0, 0, 0);
                acc[i][j] = __builtin_amdgcn_mfma_f32_16x16x32_bf16(afh[i], bfl[j], acc[i][j], 0, 0, 0);
            }
    }
    // C/D layout: col=lane&15, row=(lane>>4)*4+reg   [m89-verified]
    int cr = (lane >> 4) * 4, cc = lane & 15;
#pragma unroll
    for (int i = 0; i < 4; ++i) {
#pragma unroll
        for (int r = 0; r < 4; ++r) {
            int gr = m0 + wm + i * 16 + cr + r;
            if (gr < M) {
#pragma unroll
                for (int j = 0; j < 4; ++j)
                    C[(size_t)gr * DM + n0 + wn + j * 16 + cc] = acc[i][j][r];
            }
        }
    }
    // ---- fused attention scores: this block's 128 cols == head blockIdx.x ----
    int head = blockIdx.x;
    float asl_[4], adl_[4];
#pragma unroll
    for (int j = 0; j < 4; ++j) {
        int c = wn + j * 16 + cc;
        asl_[j] = a_s[head * HID + c];
        adl_[j] = a_d[head * HID + c];
    }
#pragma unroll
    for (int i = 0; i < 4; ++i) {
#pragma unroll
        for (int r = 0; r < 4; ++r) {
            float ps = 0.f, pd = 0.f;
#pragma unroll
            for (int j = 0; j < 4; ++j) {
                ps += acc[i][j][r] * asl_[j];
                pd += acc[i][j][r] * adl_[j];
            }
#pragma unroll
            for (int mk = 1; mk < 16; mk <<= 1) {
                ps += __shfl_xor(ps, mk);
                pd += __shfl_xor(pd, mk);
            }
            if (cc == 0) {
                int row = wm + i * 16 + (lane >> 4) * 4 + r;
                atomicAdd(&sS[row], ps);
                atomicAdd(&sD[row], pd);
            }
        }
    }
    __syncthreads();
    if (tid < 128) {
        int gr = m0 + tid;
        if (gr < M) {
            ssrc[gr * 4 + head] = sS[tid];
            sdst[gr * 4 + head] = sD[tid];
        }
    }
}

// ---------- CSR build ----------
__global__ void k_degree(const int* __restrict__ ei, int* __restrict__ deg) {
    int e = blockIdx.x * blockDim.x + threadIdx.x;
    if (e >= ET_EDGES) return;
    int d = (e < E_EDGES) ? ei[E_EDGES + e] : (e - E_EDGES);
    atomicAdd(&deg[d], 1);
}

__global__ __launch_bounds__(1024) void k_scan2(const int* __restrict__ deg,
                                                int* __restrict__ offs) {
    __shared__ int part[1025];
    int t = threadIdx.x;
    const int CH = (N_NODES + 1023) / 1024;
    int lo = t * CH, hi = lo + CH; if (hi > N_NODES) hi = N_NODES; if (lo > N_NODES) lo = N_NODES;
    int s = 0;
    for (int i = lo; i < hi; ++i) s += deg[i];
    part[t] = s;
    __syncthreads();
    if (t == 0) {
        int acc = 0;
        for (int i = 0; i < 1024; ++i) { int v = part[i]; part[i] = acc; acc += v; }
        part[1024] = acc;
    }
    __syncthreads();
    int acc = part[t];
    for (int i = lo; i < hi; ++i) { offs[i] = acc; acc += deg[i]; }
    if (t == 1023) offs[N_NODES] = part[1024];
}

__global__ void k_scatter(const int* __restrict__ ei, int* __restrict__ cursor,
                          int* __restrict__ csr_src) {
    int e = blockIdx.x * blockDim.x + threadIdx.x;
    if (e >= ET_EDGES) return;
    int sv, d;
    if (e < E_EDGES) { sv = ei[e]; d = ei[E_EDGES + e]; } else { sv = d = e - E_EDGES; }
    int pos = atomicAdd(&cursor[d], 1);
    csr_src[pos] = sv;
}

__global__ void k_gbounds(const int* __restrict__ batch, int* __restrict__ gstart) {
    int i = blockIdx.x * blockDim.x + threadIdx.x;
    if (i >= N_NODES) return;
    int b = batch[i];
    int p = (i == 0) ? -1 : batch[i - 1];
    for (int g = p + 1; g <= b; ++g) gstart[g] = i;
    if (i == N_NODES - 1)
        for (int g = b + 1; g <= G_GRAPHS; ++g) gstart[g] = N_NODES;
}

// ---------- softmax max & denom per (node,head): single-pass online ----------
__global__ __launch_bounds__(256) void k_msum(const float* __restrict__ ssrc,
                                              const float* __restrict__ sdst,
                                              const int* __restrict__ offs,
                                              const int* __restrict__ csr_src,
                                              float* __restrict__ msum,
                                              float* __restrict__ ssum) {
    int t = blockIdx.x * 256 + threadIdx.x;
    if (t >= N_NODES * HEADS) return;
    int n = t >> 2, h = t & 3;
    int beg = offs[n], end = offs[n + 1];
    float sdh = sdst[n * 4 + h];
    float m = -1e30f, s = 0.f;
    for (int e = beg; e < end; ++e) {
        float sc = ssrc[csr_src[e] * 4 + h] + sdh;
        sc = sc > 0.f ? sc : NEG_SLOPE * sc;
        if (sc > m) { s = s * __expf(m - sc) + 1.f; m = sc; }
        else s += __expf(sc - m);
    }
    msum[t] = m; ssum[t] = s;
}

// ---------- GAT aggregate: one wave per dst node, 4-edge pipelined ----------
__global__ __launch_bounds__(256) void k_aggregate(const float* __restrict__ H,
                                                   const float* __restrict__ ssrc,
                                                   const float* __restrict__ sdst,
                                                   const float* __restrict__ msum,
                                                   const float* __restrict__ ssum,
                                                   const int* __restrict__ offs,
                                                   const int* __restrict__ csr_src,
                                                   const float* __restrict__ bias,
                                                   float* __restrict__ out) {
    int wave = threadIdx.x >> 6, lane = threadIdx.x & 63;
    int n = blockIdx.x * 4 + wave;
    if (n >= N_NODES) return;
    int beg = offs[n], end = offs[n + 1];
    int hl = lane >> 4;                       // lane's 8 features all in head lane>>4
    float sdh = sdst[n * 4 + hl];
    float mh = msum[n * 4 + hl];
    float inv = 1.f / ssum[n * 4 + hl];
    float acc[8] = { 0.f, 0.f, 0.f, 0.f, 0.f, 0.f, 0.f, 0.f };
    int e = beg;
    for (; e + 4 <= end; e += 4) {
        int sv0 = csr_src[e], sv1 = csr_src[e + 1];
        int sv2 = csr_src[e + 2], sv3 = csr_src[e + 3];
        float s0 = ssrc[sv0 * 4 + hl], s1 = ssrc[sv1 * 4 + hl];
        float s2 = ssrc[sv2 * 4 + hl], s3 = ssrc[sv3 * 4 + hl];
        const float* hp0 = H + (size_t)sv0 * DM + lane * 8;
        const float* hp1 = H + (size_t)sv1 * DM + lane * 8;
        const float* hp2 = H + (size_t)sv2 * DM + lane * 8;
        const float* hp3 = H + (size_t)sv3 * DM + lane * 8;
        float4 h0a = *(const float4*)hp0, h0b = *(const float4*)(hp0 + 4);
        float4 h1a = *(const float4*)hp1, h1b = *(const float4*)(hp1 + 4);
        float4 h2a = *(const float4*)hp2, h2b = *(const float4*)(hp2 + 4);
        float4 h3a = *(const float4*)hp3, h3b = *(const float4*)(hp3 + 4);
        s0 += sdh; s0 = s0 > 0.f ? s0 : NEG_SLOPE * s0;
        s1 += sdh; s1 = s1 > 0.f ? s1 : NEG_SLOPE * s1;
        s2 += sdh; s2 = s2 > 0.f ? s2 : NEG_SLOPE * s2;
        s3 += sdh; s3 = s3 > 0.f ? s3 : NEG_SLOPE * s3;
        float a0 = __expf(s0 - mh) * inv, a1 = __expf(s1 - mh) * inv;
        float a2 = __expf(s2 - mh) * inv, a3 = __expf(s3 - mh) * inv;
        acc[0] += a0 * h0a.x + a1 * h1a.x + a2 * h2a.x + a3 * h3a.x;
        acc[1] += a0 * h0a.y + a1 * h1a.y + a2 * h2a.y + a3 * h3a.y;
        acc[2] += a0 * h0a.z + a1 * h1a.z + a2 * h2a.z + a3 * h3a.z;
        acc[3] += a0 * h0a.w + a1 * h1a.w + a2 * h2a.w + a3 * h3a.w;
        acc[4] += a0 * h0b.x + a1 * h1b.x + a2 * h2b.x + a3 * h3b.x;
        acc[5] += a0 * h0b.y + a1 * h1b.y + a2 * h2b.y + a3 * h3b.y;
        acc[6] += a0 * h0b.z + a1 * h1b.z + a2 * h2b.z + a3 * h3b.z;
        acc[7] += a0 * h0b.w + a1 * h1b.w + a2 * h2b.w + a3 * h3b.w;
    }
    for (; e < end; ++e) {
        int sv = csr_src[e];
        float sc = ssrc[sv * 4 + hl] + sdh;
        sc = sc > 0.f ? sc : NEG_SLOPE * sc;
        float alpha = __expf(sc - mh) * inv;
        const float* hp = H + (size_t)sv * DM + lane * 8;
        float4 h0 = *(const float4*)hp;
        float4 h1 = *(const float4*)(hp + 4);
        acc[0] += alpha * h0.x; acc[1] += alpha * h0.y;
        acc[2] += alpha * h0.z; acc[3] += alpha * h0.w;
        acc[4] += alpha * h1.x; acc[5] += alpha * h1.y;
        acc[6] += alpha * h1.z; acc[7] += alpha * h1.w;
    }
    const float* bp = bias + lane * 8;
    float4 b0 = *(const float4*)bp;
    float4 b1 = *(const float4*)(bp + 4);
    float* op = out + (size_t)n * DM + lane * 8;
    float4 o0, o1;
    o0.x = acc[0] + b0.x; o0.y = acc[1] + b0.y; o0.z = acc[2] + b0.z; o0.w = acc[3] + b0.w;
    o1.x = acc[4] + b1.x; o1.y = acc[5] + b1.y; o1.z = acc[6] + b1.z; o1.w = acc[7] + b1.w;
    *(float4*)op = o0;
    *(float4*)(op + 4) = o1;
}

// ---------- BatchNorm stats: contiguous row slabs, coalesced full-row reads ----------
#define BN_ROWS 125   // 400 blocks x 125 rows
__global__ __launch_bounds__(256) void k_bnstats(const float* __restrict__ X,
                                                 float* __restrict__ stat) {
    int t = threadIdx.x;
    int c2 = t * 2;                       // this thread owns features c2, c2+1
    int beg = blockIdx.x * BN_ROWS;
    int end = beg + BN_ROWS; if (end > N_NODES) end = N_NODES;
    float s0 = 0.f, s1 = 0.f, q0 = 0.f, q1 = 0.f;
    for (int n = beg; n < end; ++n) {     // 256 threads x float2 = one full 2KB row
        float2 v = *(const float2*)&X[(size_t)n * DM + c2];
        s0 += v.x; s1 += v.y;
        q0 += v.x * v.x; q1 += v.y * v.y;
    }
    atomicAdd(&stat[c2], s0);
    atomicAdd(&stat[c2 + 1], s1);
    atomicAdd(&stat[512 + c2], q0);
    atomicAdd(&stat[512 + c2 + 1], q1);
}

__global__ void k_bnfin(const float* __restrict__ stat, const float* __restrict__ g,
                        const float* __restrict__ be, float* __restrict__ scale,
                        float* __restrict__ shift) {
    int f = blockIdx.x * blockDim.x + threadIdx.x;
    if (f >= DM) return;
    float mu = stat[f] * (1.f / (float)N_NODES);
    float var = stat[512 + f] * (1.f / (float)N_NODES) - mu * mu;
    var = fmaxf(var, 0.f);
    float rs = rsqrtf(var + BN_EPS);
    float sc = g[f] * rs;
    scale[f] = sc;
    shift[f] = be[f] - mu * sc;
}

// ---------- graph pooling, fused final BN+ReLU: one wave per graph ----------
__global__ __launch_bounds__(64) void k_pool(const float* __restrict__ X,
                                             const int* __restrict__ gstart,
                                             const float* __restrict__ bnsc,
                                             const float* __restrict__ bnsh,
                                             float* __restrict__ pool) {
    int g = blockIdx.x, t = threadIdx.x;   // 64 threads, 8 feats each
    int beg = gstart[g], end = gstart[g + 1];
    const float* sp = bnsc + t * 8;
    const float* tp = bnsh + t * 8;
    float sc[8], sh[8];
#pragma unroll
    for (int j = 0; j < 8; ++j) { sc[j] = sp[j]; sh[j] = tp[j]; }
    float sum[8] = { 0 }, mx[8];
#pragma unroll
    for (int j = 0; j < 8; ++j) mx[j] = -1e30f;
    for (int nn = beg; nn < end; ++nn) {
        const float* xp = X + (size_t)nn * DM + t * 8;
        float4 x0 = *(const float4*)xp;
        float4 x1 = *(const float4*)(xp + 4);
        float f[8] = { x0.x, x0.y, x0.z, x0.w, x1.x, x1.y, x1.z, x1.w };
#pragma unroll
        for (int j = 0; j < 8; ++j) {
            f[j] = fmaxf(f[j] * sc[j] + sh[j], 0.f);
            sum[j] += f[j]; mx[j] = fmaxf(mx[j], f[j]);
        }
    }
    float cnt = (float)(end - beg);
    float inv = cnt > 0.f ? 1.f / cnt : 0.f;
#pragma unroll
    for (int j = 0; j < 8; ++j) {
        pool[(size_t)g * 1024 + t * 8 + j] = sum[j] * inv;
        pool[(size_t)g * 1024 + 512 + t * 8 + j] = cnt > 0.f ? mx[j] : 0.f;
    }
}

// ---------- MLP head: one block per graph; f32 throughout ----------
__global__ __launch_bounds__(128) void k_mlp(const float* __restrict__ pool,
                                             const float* __restrict__ c1w,
                                             const float* __restrict__ c1b,
                                             const float* __restrict__ c2w,
                                             const float* __restrict__ c2b,
                                             const float* __restrict__ c3w,
                                             const float* __restrict__ c3b,
                                             float* __restrict__ out) {
    __shared__ float row[1024];
    __shared__ float h1[128];
    __shared__ float h2[64];
    int g = blockIdx.x, t = threadIdx.x;
    for (int i = t; i < 1024; i += 128) row[i] = pool[(size_t)g * 1024 + i];
    __syncthreads();
    float a1 = c1b[t];
#pragma unroll 8
    for (int k = 0; k < 1024; ++k) a1 += row[k] * c1w[k * 128 + t];
    h1[t] = fmaxf(a1, 0.f);
    __syncthreads();
    if (t < 64) {
        float a2 = c2b[t];
#pragma unroll 8
        for (int k = 0; k < 128; ++k) a2 += h1[k] * c2w[k * 64 + t];
        h2[t] = fmaxf(a2, 0.f);
    }
    __syncthreads();
    if (t < 64) {
        float p = h2[t] * c3w[t];
#pragma unroll
        for (int off = 32; off > 0; off >>= 1) p += __shfl_down(p, off);
        if (t == 0) {
            float z = p + c3b[0];
            out[g] = 1.f / (1.f + __expf(-z));      // float32 output
        }
    }
}

extern "C" void kernel_launch(void* const* d_in, const int* in_sizes, int n_in,
                              void* d_out, int out_size, void* d_ws, size_t ws_size,
                              hipStream_t stream) {
    const float* x = (const float*)d_in[0];
    const int* ei = (const int*)d_in[1];
    const int* batch = (const int*)d_in[2];
    const float* c1w = (const float*)d_in[21];
    const float* c1b = (const float*)d_in[22];
    const float* c2w = (const float*)d_in[23];
    const float* c2b = (const float*)d_in[24];
    const float* c3w = (const float*)d_in[25];
    const float* c3b = (const float*)d_in[26];

    char* p = (char*)d_ws;
    auto carve = [&](size_t bytes) -> char* {
        char* r = p; p += (bytes + 255) & ~(size_t)255; return r;
    };
    float*    A      = (float*)carve((size_t)N_NODES * DM * 4);   // aggregate output (pre-BN)
    float*    Hb     = (float*)carve((size_t)N_NODES * DM * 4);   // h = f(x)@W
    ushort_t* Wh     = (ushort_t*)carve((size_t)DM * DM * 2);     // W^T hi (bf16)
    ushort_t* Wl     = (ushort_t*)carve((size_t)DM * DM * 2);     // W^T lo (bf16)
    float*    ssrc   = (float*)carve((size_t)N_NODES * 4 * 4);
    float*    sdst   = (float*)carve((size_t)N_NODES * 4 * 4);
    float*    msum   = (float*)carve((size_t)N_NODES * 4 * 4);
    float*    ssum   = (float*)carve((size_t)N_NODES * 4 * 4);
    int*      deg    = (int*)carve((size_t)N_NODES * 4);
    int*      offs   = (int*)carve((size_t)(N_NODES + 1) * 4);
    int*      cursor = (int*)carve((size_t)N_NODES * 4);
    int*      csrsrc = (int*)carve((size_t)ET_EDGES * 4);
    float*    bnstat = (float*)carve(1024 * 4);
    float*    bnscale= (float*)carve(512 * 4);
    float*    bnshift= (float*)carve(512 * 4);
    int*      gstart = (int*)carve((size_t)(G_GRAPHS + 1) * 4);
    float*    pool   = (float*)carve((size_t)G_GRAPHS * 1024 * 4);

    // --- CSR by dst (self-loops appended) + graph bounds ---
    hipMemsetAsync(deg, 0, (size_t)N_NODES * 4, stream);
    k_degree<<<(ET_EDGES + 255) / 256, 256, 0, stream>>>(ei, deg);
    k_scan2<<<1, 1024, 0, stream>>>(deg, offs);
    hipMemcpyAsync(cursor, offs, (size_t)N_NODES * 4, hipMemcpyDeviceToDevice, stream);
    k_scatter<<<(ET_EDGES + 255) / 256, 256, 0, stream>>>(ei, cursor, csrsrc);
    k_gbounds<<<(N_NODES + 255) / 256, 256, 0, stream>>>(batch, gstart);

    const float* xin = x;
    const float* bns = nullptr;   // BN scale/shift applied to mgemm input (fused)
    const float* bnh = nullptr;
    for (int l = 0; l < 3; ++l) {
        int K = (l == 0) ? F_IN : DM;
        const float* W   = (const float*)d_in[3 + 6 * l];
        const float* as_ = (const float*)d_in[4 + 6 * l];
        const float* ad_ = (const float*)d_in[5 + 6 * l];
        const float* bia = (const float*)d_in[6 + 6 * l];
        const float* gam = (const float*)d_in[7 + 6 * l];
        const float* bet = (const float*)d_in[8 + 6 * l];

        k_wprep<<<(K * DM + 255) / 256, 256, 0, stream>>>(W, Wh, Wl, K);
        k_mgemm<<<dim3(4, (N_NODES + 127) / 128), 256, 0, stream>>>(
            xin, Wh, Wl, bns, bnh, as_, ad_, Hb, ssrc, sdst, N_NODES, K);
        k_msum<<<(N_NODES * HEADS + 255) / 256, 256, 0, stream>>>(ssrc, sdst, offs, csrsrc, msum, ssum);
        k_aggregate<<<(N_NODES + 3) / 4, 256, 0, stream>>>(Hb, ssrc, sdst, msum, ssum, offs, csrsrc, bia, A);
        hipMemsetAsync(bnstat, 0, 1024 * 4, stream);
        k_bnstats<<<(N_NODES + BN_ROWS - 1) / BN_ROWS, 256, 0, stream>>>(A, bnstat);
        k_bnfin<<<2, 256, 0, stream>>>(bnstat, gam, bet, bnscale, bnshift);
        xin = A; bns = bnscale; bnh = bnshift;
    }
    k_pool<<<G_GRAPHS, 64, 0, stream>>>(A, gstart, bnscale, bnshift, pool);
    k_mlp<<<G_GRAPHS, 128, 0, stream>>>(pool, c1w, c1b, c2w, c2b, c3w, c3b,
                                        (float*)d_out);
}

// Round 10
// 919.146 us; speedup vs baseline: 1.7625x; 1.1237x over previous
//
#include <hip/hip_runtime.h>

#define N_NODES 50000
#define E_EDGES 200000
#define ET_EDGES (E_EDGES + N_NODES)
#define G_GRAPHS 2000
#define F_IN 64
#define HID 128
#define HEADS 4
#define DM 512
#define BN_EPS 1e-5f
#define NEG_SLOPE 0.2f

typedef unsigned short ushort_t;
typedef float floatx4 __attribute__((ext_vector_type(4)));
typedef short short8 __attribute__((ext_vector_type(8)));

__device__ __forceinline__ float b2f(unsigned int u) {
    union { unsigned int i; float f; } v; v.i = u << 16; return v.f;
}
__device__ __forceinline__ ushort_t f2b(float f) {
    union { float f; unsigned int i; } v; v.f = f;
    unsigned int r = v.i + 0x7FFFu + ((v.i >> 16) & 1u);   // RNE
    return (ushort_t)(r >> 16);
}
__device__ __forceinline__ void unpack8(uint4 v, float* f) {
    f[0] = b2f(v.x & 0xffffu); f[1] = b2f(v.x >> 16);
    f[2] = b2f(v.y & 0xffffu); f[3] = b2f(v.y >> 16);
    f[4] = b2f(v.z & 0xffffu); f[5] = b2f(v.z >> 16);
    f[6] = b2f(v.w & 0xffffu); f[7] = b2f(v.w >> 16);
}
// split f32 into bf16 hi + bf16 lo:  x ≈ hi + lo, |err| <= 2^-18 |x|
__device__ __forceinline__ void split_bf(float x, ushort_t& h, ushort_t& l) {
    h = f2b(x);
    l = f2b(x - b2f(h));
}

// ---------- W[K,512] f32 -> Wt_hi/Wt_lo [512,K] bf16 (transpose + split) ----------
__global__ __launch_bounds__(256) void k_wprep(const float* __restrict__ W,
                                               ushort_t* __restrict__ Wh,
                                               ushort_t* __restrict__ Wl, int K) {
    int t = blockIdx.x * 256 + threadIdx.x;
    if (t >= K * DM) return;
    int k = t >> 9, n = t & 511;            // t = k*512 + n (coalesced read)
    ushort_t h, l; split_bf(W[t], h, l);
    Wh[(size_t)n * K + k] = h;
    Wl[(size_t)n * K + k] = l;
}

// ---------- MFMA GEMM, f32-faithful, fused BN-on-input + attention scores ----------
// C[M,512](bf16) = f(A)[M,K] @ W[K,512], f(a)=max(a*bnsc+bnsh,0) if bnsc else a.
// Each block's 128 output cols = exactly one head -> ssrc/sdst computed in epilogue
// from the f32 accumulators (pre-rounding).
#define LDST 40   // 32 + 8 pad (bf16 elems), 80B rows
__global__ __launch_bounds__(256) void k_mgemm(const float* __restrict__ A,
                                               const ushort_t* __restrict__ Bh,
                                               const ushort_t* __restrict__ Bl,
                                               const float* __restrict__ bnsc,
                                               const float* __restrict__ bnsh,
                                               const float* __restrict__ a_s,
                                               const float* __restrict__ a_d,
                                               ushort_t* __restrict__ C,
                                               float* __restrict__ ssrc,
                                               float* __restrict__ sdst,
                                               int M, int K) {
    __shared__ __align__(16) ushort_t Ash[128 * LDST];
    __shared__ __align__(16) ushort_t Asl[128 * LDST];
    __shared__ __align__(16) ushort_t Bsh[128 * LDST];
    __shared__ __align__(16) ushort_t Bsl[128 * LDST];
    __shared__ float sS[128], sD[128];
    int tid = threadIdx.x;
    int lane = tid & 63, wave = tid >> 6;
    int m0 = blockIdx.y * 128, n0 = blockIdx.x * 128;
    int wm = (wave >> 1) * 64, wn = (wave & 1) * 64;
    int r0 = tid >> 2, kv = tid & 3;
    floatx4 acc[4][4] = {};
    int rA1 = m0 + r0;      if (rA1 >= M) rA1 = M - 1;
    int rA2 = m0 + r0 + 64; if (rA2 >= M) rA2 = M - 1;
    const float* pa1 = A + (size_t)rA1 * K + kv * 8;
    const float* pa2 = A + (size_t)rA2 * K + kv * 8;
    const ushort_t* pbh1 = Bh + (size_t)(n0 + r0) * K + kv * 8;
    const ushort_t* pbh2 = Bh + (size_t)(n0 + r0 + 64) * K + kv * 8;
    const ushort_t* pbl1 = Bl + (size_t)(n0 + r0) * K + kv * 8;
    const ushort_t* pbl2 = Bl + (size_t)(n0 + r0 + 64) * K + kv * 8;
    int rF = lane & 15, kq = (lane >> 4) * 8;
    if (tid < 128) { sS[tid] = 0.f; sD[tid] = 0.f; }
    for (int k0 = 0; k0 < K; k0 += 32) {
        float4 a1a = *(const float4*)(pa1 + k0);
        float4 a1b = *(const float4*)(pa1 + k0 + 4);
        float4 a2a = *(const float4*)(pa2 + k0);
        float4 a2b = *(const float4*)(pa2 + k0 + 4);
        uint4 b1h = *(const uint4*)(pbh1 + k0);
        uint4 b2h = *(const uint4*)(pbh2 + k0);
        uint4 b1l = *(const uint4*)(pbl1 + k0);
        uint4 b2l = *(const uint4*)(pbl2 + k0);
        float v1[8] = { a1a.x, a1a.y, a1a.z, a1a.w, a1b.x, a1b.y, a1b.z, a1b.w };
        float v2[8] = { a2a.x, a2a.y, a2a.z, a2a.w, a2b.x, a2b.y, a2b.z, a2b.w };
        if (bnsc) {   // fused BN-apply + ReLU on the input features
            const float* sp = bnsc + k0 + kv * 8;
            const float* tp = bnsh + k0 + kv * 8;
#pragma unroll
            for (int j = 0; j < 8; ++j) {
                float sj = sp[j], tj = tp[j];
                v1[j] = fmaxf(v1[j] * sj + tj, 0.f);
                v2[j] = fmaxf(v2[j] * sj + tj, 0.f);
            }
        }
        uint4 a1h, a1l, a2h, a2l;
        unsigned* p1h = (unsigned*)&a1h; unsigned* p1l = (unsigned*)&a1l;
        unsigned* p2h = (unsigned*)&a2h; unsigned* p2l = (unsigned*)&a2l;
#pragma unroll
        for (int j = 0; j < 4; ++j) {
            ushort_t h0, l0, h1, l1;
            split_bf(v1[2 * j], h0, l0); split_bf(v1[2 * j + 1], h1, l1);
            p1h[j] = (unsigned)h0 | ((unsigned)h1 << 16);
            p1l[j] = (unsigned)l0 | ((unsigned)l1 << 16);
            split_bf(v2[2 * j], h0, l0); split_bf(v2[2 * j + 1], h1, l1);
            p2h[j] = (unsigned)h0 | ((unsigned)h1 << 16);
            p2l[j] = (unsigned)l0 | ((unsigned)l1 << 16);
        }
        __syncthreads();
        *(uint4*)&Ash[r0 * LDST + kv * 8] = a1h;
        *(uint4*)&Asl[r0 * LDST + kv * 8] = a1l;
        *(uint4*)&Ash[(r0 + 64) * LDST + kv * 8] = a2h;
        *(uint4*)&Asl[(r0 + 64) * LDST + kv * 8] = a2l;
        *(uint4*)&Bsh[r0 * LDST + kv * 8] = b1h;
        *(uint4*)&Bsl[r0 * LDST + kv * 8] = b1l;
        *(uint4*)&Bsh[(r0 + 64) * LDST + kv * 8] = b2h;
        *(uint4*)&Bsl[(r0 + 64) * LDST + kv * 8] = b2l;
        __syncthreads();
        short8 afh[4], afl[4], bfh[4], bfl[4];
#pragma unroll
        for (int i = 0; i < 4; ++i) {
            afh[i] = *(const short8*)&Ash[(wm + i * 16 + rF) * LDST + kq];
            afl[i] = *(const short8*)&Asl[(wm + i * 16 + rF) * LDST + kq];
        }
#pragma unroll
        for (int j = 0; j < 4; ++j) {
            bfh[j] = *(const short8*)&Bsh[(wn + j * 16 + rF) * LDST + kq];
            bfl[j] = *(const short8*)&Bsl[(wn + j * 16 + rF) * LDST + kq];
        }
#pragma unroll
        for (int i = 0; i < 4; ++i)
#pragma unroll
            for (int j = 0; j < 4; ++j) {
                acc[i][j] = __builtin_amdgcn_mfma_f32_16x16x32_bf16(afh[i], bfh[j], acc[i][j], 0, 0, 0);
                acc[i][j] = __builtin_amdgcn_mfma_f32_16x16x32_bf16(afl[i], bfh[j], acc[i][j], 0, 0, 0);
                acc[i][j] = __builtin_amdgcn_mfma_f32_16x16x32_bf16(afh[i], bfl[j], acc[i][j], 0, 0, 0);
            }
    }
    // C/D layout: col=lane&15, row=(lane>>4)*4+reg   [m89-verified]
    int cr = (lane >> 4) * 4, cc = lane & 15;
#pragma unroll
    for (int i = 0; i < 4; ++i) {
#pragma unroll
        for (int r = 0; r < 4; ++r) {
            int gr = m0 + wm + i * 16 + cr + r;
            if (gr < M) {
#pragma unroll
                for (int j = 0; j < 4; ++j)
                    C[(size_t)gr * DM + n0 + wn + j * 16 + cc] = f2b(acc[i][j][r]);
            }
        }
    }
    // ---- fused attention scores (f32 acc, pre-rounding): 128 cols == one head ----
    int head = blockIdx.x;
    float asl_[4], adl_[4];
#pragma unroll
    for (int j = 0; j < 4; ++j) {
        int c = wn + j * 16 + cc;
        asl_[j] = a_s[head * HID + c];
        adl_[j] = a_d[head * HID + c];
    }
#pragma unroll
    for (int i = 0; i < 4; ++i) {
#pragma unroll
        for (int r = 0; r < 4; ++r) {
            float ps = 0.f, pd = 0.f;
#pragma unroll
            for (int j = 0; j < 4; ++j) {
                ps += acc[i][j][r] * asl_[j];
                pd += acc[i][j][r] * adl_[j];
            }
#pragma unroll
            for (int mk = 1; mk < 16; mk <<= 1) {
                ps += __shfl_xor(ps, mk);
                pd += __shfl_xor(pd, mk);
            }
            if (cc == 0) {
                int row = wm + i * 16 + (lane >> 4) * 4 + r;
                atomicAdd(&sS[row], ps);
                atomicAdd(&sD[row], pd);
            }
        }
    }
    __syncthreads();
    if (tid < 128) {
        int gr = m0 + tid;
        if (gr < M) {
            ssrc[gr * 4 + head] = sS[tid];
            sdst[gr * 4 + head] = sD[tid];
        }
    }
}

// ---------- CSR build ----------
__global__ void k_degree(const int* __restrict__ ei, int* __restrict__ deg) {
    int e = blockIdx.x * blockDim.x + threadIdx.x;
    if (e >= ET_EDGES) return;
    int d = (e < E_EDGES) ? ei[E_EDGES + e] : (e - E_EDGES);
    atomicAdd(&deg[d], 1);
}

__global__ __launch_bounds__(1024) void k_scan2(const int* __restrict__ deg,
                                                int* __restrict__ offs) {
    __shared__ int part[1025];
    int t = threadIdx.x;
    const int CH = (N_NODES + 1023) / 1024;
    int lo = t * CH, hi = lo + CH; if (hi > N_NODES) hi = N_NODES; if (lo > N_NODES) lo = N_NODES;
    int s = 0;
    for (int i = lo; i < hi; ++i) s += deg[i];
    part[t] = s;
    __syncthreads();
    if (t == 0) {
        int acc = 0;
        for (int i = 0; i < 1024; ++i) { int v = part[i]; part[i] = acc; acc += v; }
        part[1024] = acc;
    }
    __syncthreads();
    int acc = part[t];
    for (int i = lo; i < hi; ++i) { offs[i] = acc; acc += deg[i]; }
    if (t == 1023) offs[N_NODES] = part[1024];
}

__global__ void k_scatter(const int* __restrict__ ei, int* __restrict__ cursor,
                          int* __restrict__ csr_src) {
    int e = blockIdx.x * blockDim.x + threadIdx.x;
    if (e >= ET_EDGES) return;
    int sv, d;
    if (e < E_EDGES) { sv = ei[e]; d = ei[E_EDGES + e]; } else { sv = d = e - E_EDGES; }
    int pos = atomicAdd(&cursor[d], 1);
    csr_src[pos] = sv;
}

__global__ void k_gbounds(const int* __restrict__ batch, int* __restrict__ gstart) {
    int i = blockIdx.x * blockDim.x + threadIdx.x;
    if (i >= N_NODES) return;
    int b = batch[i];
    int p = (i == 0) ? -1 : batch[i - 1];
    for (int g = p + 1; g <= b; ++g) gstart[g] = i;
    if (i == N_NODES - 1)
        for (int g = b + 1; g <= G_GRAPHS; ++g) gstart[g] = N_NODES;
}

// ---------- GAT softmax + aggregate, fully fused: one wave per dst node ----------
// pass 1: per-head online (m,s) using the 16 lanes of each head group;
// pass 2: 4-edge pipelined weighted gather of bf16 H rows.
__global__ __launch_bounds__(256) void k_aggregate(const ushort_t* __restrict__ H,
                                                   const float* __restrict__ ssrc,
                                                   const float* __restrict__ sdst,
                                                   const int* __restrict__ offs,
                                                   const int* __restrict__ csr_src,
                                                   const float* __restrict__ bias,
                                                   float* __restrict__ out) {
    int wave = threadIdx.x >> 6, lane = threadIdx.x & 63;
    int n = blockIdx.x * 4 + wave;
    if (n >= N_NODES) return;
    int beg = offs[n], end = offs[n + 1];
    int hl = lane >> 4, li = lane & 15;       // head group, index within group
    float sdh = sdst[n * 4 + hl];
    // ---- pass 1: online softmax stats for head hl ----
    float m = -1e30f, s = 0.f;
    for (int e = beg + li; e < end; e += 16) {
        float sc = ssrc[csr_src[e] * 4 + hl] + sdh;
        sc = sc > 0.f ? sc : NEG_SLOPE * sc;
        if (sc > m) { s = s * __expf(m - sc) + 1.f; m = sc; }
        else s += __expf(sc - m);
    }
#pragma unroll
    for (int mk = 1; mk < 16; mk <<= 1) {     // xor<16 stays inside head group
        float om = __shfl_xor(m, mk), os = __shfl_xor(s, mk);
        float mn = fmaxf(m, om);
        s = s * __expf(m - mn) + os * __expf(om - mn);
        m = mn;
    }
    float mh = m, inv = 1.f / s;
    // ---- pass 2: weighted gather (bf16 rows, 16B/lane) ----
    float acc[8] = { 0.f, 0.f, 0.f, 0.f, 0.f, 0.f, 0.f, 0.f };
    int e = beg;
    for (; e + 4 <= end; e += 4) {
        int sv0 = csr_src[e], sv1 = csr_src[e + 1];
        int sv2 = csr_src[e + 2], sv3 = csr_src[e + 3];
        float s0 = ssrc[sv0 * 4 + hl], s1 = ssrc[sv1 * 4 + hl];
        float s2 = ssrc[sv2 * 4 + hl], s3 = ssrc[sv3 * 4 + hl];
        uint4 h0 = *(const uint4*)&H[(size_t)sv0 * DM + lane * 8];
        uint4 h1 = *(const uint4*)&H[(size_t)sv1 * DM + lane * 8];
        uint4 h2 = *(const uint4*)&H[(size_t)sv2 * DM + lane * 8];
        uint4 h3 = *(const uint4*)&H[(size_t)sv3 * DM + lane * 8];
        s0 += sdh; s0 = s0 > 0.f ? s0 : NEG_SLOPE * s0;
        s1 += sdh; s1 = s1 > 0.f ? s1 : NEG_SLOPE * s1;
        s2 += sdh; s2 = s2 > 0.f ? s2 : NEG_SLOPE * s2;
        s3 += sdh; s3 = s3 > 0.f ? s3 : NEG_SLOPE * s3;
        float a0 = __expf(s0 - mh) * inv, a1 = __expf(s1 - mh) * inv;
        float a2 = __expf(s2 - mh) * inv, a3 = __expf(s3 - mh) * inv;
        float f0[8], f1[8], f2[8], f3[8];
        unpack8(h0, f0); unpack8(h1, f1); unpack8(h2, f2); unpack8(h3, f3);
#pragma unroll
        for (int j = 0; j < 8; ++j)
            acc[j] += a0 * f0[j] + a1 * f1[j] + a2 * f2[j] + a3 * f3[j];
    }
    for (; e < end; ++e) {
        int sv = csr_src[e];
        float sc = ssrc[sv * 4 + hl] + sdh;
        sc = sc > 0.f ? sc : NEG_SLOPE * sc;
        float alpha = __expf(sc - mh) * inv;
        uint4 hv = *(const uint4*)&H[(size_t)sv * DM + lane * 8];
        float f[8]; unpack8(hv, f);
#pragma unroll
        for (int j = 0; j < 8; ++j) acc[j] += alpha * f[j];
    }
    const float* bp = bias + lane * 8;
    float4 b0 = *(const float4*)bp;
    float4 b1 = *(const float4*)(bp + 4);
    float* op = out + (size_t)n * DM + lane * 8;
    float4 o0, o1;
    o0.x = acc[0] + b0.x; o0.y = acc[1] + b0.y; o0.z = acc[2] + b0.z; o0.w = acc[3] + b0.w;
    o1.x = acc[4] + b1.x; o1.y = acc[5] + b1.y; o1.z = acc[6] + b1.z; o1.w = acc[7] + b1.w;
    *(float4*)op = o0;
    *(float4*)(op + 4) = o1;
}

// ---------- BatchNorm stats: contiguous row slabs, coalesced full-row reads ----------
#define BN_ROWS 125   // 400 blocks x 125 rows
__global__ __launch_bounds__(256) void k_bnstats(const float* __restrict__ X,
                                                 float* __restrict__ stat) {
    int t = threadIdx.x;
    int c2 = t * 2;                       // this thread owns features c2, c2+1
    int beg = blockIdx.x * BN_ROWS;
    int end = beg + BN_ROWS; if (end > N_NODES) end = N_NODES;
    float s0 = 0.f, s1 = 0.f, q0 = 0.f, q1 = 0.f;
    for (int n = beg; n < end; ++n) {     // 256 threads x float2 = one full 2KB row
        float2 v = *(const float2*)&X[(size_t)n * DM + c2];
        s0 += v.x; s1 += v.y;
        q0 += v.x * v.x; q1 += v.y * v.y;
    }
    atomicAdd(&stat[c2], s0);
    atomicAdd(&stat[c2 + 1], s1);
    atomicAdd(&stat[512 + c2], q0);
    atomicAdd(&stat[512 + c2 + 1], q1);
}

__global__ void k_bnfin(const float* __restrict__ stat, const float* __restrict__ g,
                        const float* __restrict__ be, float* __restrict__ scale,
                        float* __restrict__ shift) {
    int f = blockIdx.x * blockDim.x + threadIdx.x;
    if (f >= DM) return;
    float mu = stat[f] * (1.f / (float)N_NODES);
    float var = stat[512 + f] * (1.f / (float)N_NODES) - mu * mu;
    var = fmaxf(var, 0.f);
    float rs = rsqrtf(var + BN_EPS);
    float sc = g[f] * rs;
    scale[f] = sc;
    shift[f] = be[f] - mu * sc;
}

// ---------- graph pooling, fused final BN+ReLU: one wave per graph ----------
__global__ __launch_bounds__(64) void k_pool(const float* __restrict__ X,
                                             const int* __restrict__ gstart,
                                             const float* __restrict__ bnsc,
                                             const float* __restrict__ bnsh,
                                             float* __restrict__ pool) {
    int g = blockIdx.x, t = threadIdx.x;   // 64 threads, 8 feats each
    int beg = gstart[g], end = gstart[g + 1];
    const float* sp = bnsc + t * 8;
    const float* tp = bnsh + t * 8;
    float sc[8], sh[8];
#pragma unroll
    for (int j = 0; j < 8; ++j) { sc[j] = sp[j]; sh[j] = tp[j]; }
    float sum[8] = { 0 }, mx[8];
#pragma unroll
    for (int j = 0; j < 8; ++j) mx[j] = -1e30f;
    for (int nn = beg; nn < end; ++nn) {
        const float* xp = X + (size_t)nn * DM + t * 8;
        float4 x0 = *(const float4*)xp;
        float4 x1 = *(const float4*)(xp + 4);
        float f[8] = { x0.x, x0.y, x0.z, x0.w, x1.x, x1.y, x1.z, x1.w };
#pragma unroll
        for (int j = 0; j < 8; ++j) {
            f[j] = fmaxf(f[j] * sc[j] + sh[j], 0.f);
            sum[j] += f[j]; mx[j] = fmaxf(mx[j], f[j]);
        }
    }
    float cnt = (float)(end - beg);
    float inv = cnt > 0.f ? 1.f / cnt : 0.f;
#pragma unroll
    for (int j = 0; j < 8; ++j) {
        pool[(size_t)g * 1024 + t * 8 + j] = sum[j] * inv;
        pool[(size_t)g * 1024 + 512 + t * 8 + j] = cnt > 0.f ? mx[j] : 0.f;
    }
}

// ---------- MLP head: one block per graph; f32 throughout ----------
__global__ __launch_bounds__(128) void k_mlp(const float* __restrict__ pool,
                                             const float* __restrict__ c1w,
                                             const float* __restrict__ c1b,
                                             const float* __restrict__ c2w,
                                             const float* __restrict__ c2b,
                                             const float* __restrict__ c3w,
                                             const float* __restrict__ c3b,
                                             float* __restrict__ out) {
    __shared__ float row[1024];
    __shared__ float h1[128];
    __shared__ float h2[64];
    int g = blockIdx.x, t = threadIdx.x;
    for (int i = t; i < 1024; i += 128) row[i] = pool[(size_t)g * 1024 + i];
    __syncthreads();
    float a1 = c1b[t];
#pragma unroll 8
    for (int k = 0; k < 1024; ++k) a1 += row[k] * c1w[k * 128 + t];
    h1[t] = fmaxf(a1, 0.f);
    __syncthreads();
    if (t < 64) {
        float a2 = c2b[t];
#pragma unroll 8
        for (int k = 0; k < 128; ++k) a2 += h1[k] * c2w[k * 64 + t];
        h2[t] = fmaxf(a2, 0.f);
    }
    __syncthreads();
    if (t < 64) {
        float p = h2[t] * c3w[t];
#pragma unroll
        for (int off = 32; off > 0; off >>= 1) p += __shfl_down(p, off);
        if (t == 0) {
            float z = p + c3b[0];
            out[g] = 1.f / (1.f + __expf(-z));      // float32 output
        }
    }
}

extern "C" void kernel_launch(void* const* d_in, const int* in_sizes, int n_in,
                              void* d_out, int out_size, void* d_ws, size_t ws_size,
                              hipStream_t stream) {
    const float* x = (const float*)d_in[0];
    const int* ei = (const int*)d_in[1];
    const int* batch = (const int*)d_in[2];
    const float* c1w = (const float*)d_in[21];
    const float* c1b = (const float*)d_in[22];
    const float* c2w = (const float*)d_in[23];
    const float* c2b = (const float*)d_in[24];
    const float* c3w = (const float*)d_in[25];
    const float* c3b = (const float*)d_in[26];

    char* p = (char*)d_ws;
    auto carve = [&](size_t bytes) -> char* {
        char* r = p; p += (bytes + 255) & ~(size_t)255; return r;
    };
    float*    A      = (float*)carve((size_t)N_NODES * DM * 4);   // aggregate output (pre-BN)
    ushort_t* Hb     = (ushort_t*)carve((size_t)N_NODES * DM * 2);// h = f(x)@W, bf16
    ushort_t* Wh     = (ushort_t*)carve((size_t)DM * DM * 2);     // W^T hi (bf16)
    ushort_t* Wl     = (ushort_t*)carve((size_t)DM * DM * 2);     // W^T lo (bf16)
    float*    ssrc   = (float*)carve((size_t)N_NODES * 4 * 4);
    float*    sdst   = (float*)carve((size_t)N_NODES * 4 * 4);
    int*      deg    = (int*)carve((size_t)N_NODES * 4);
    int*      offs   = (int*)carve((size_t)(N_NODES + 1) * 4);
    int*      cursor = (int*)carve((size_t)N_NODES * 4);
    int*      csrsrc = (int*)carve((size_t)ET_EDGES * 4);
    float*    bnstat = (float*)carve(1024 * 4);
    float*    bnscale= (float*)carve(512 * 4);
    float*    bnshift= (float*)carve(512 * 4);
    int*      gstart = (int*)carve((size_t)(G_GRAPHS + 1) * 4);
    float*    pool   = (float*)carve((size_t)G_GRAPHS * 1024 * 4);

    // --- CSR by dst (self-loops appended) + graph bounds ---
    hipMemsetAsync(deg, 0, (size_t)N_NODES * 4, stream);
    k_degree<<<(ET_EDGES + 255) / 256, 256, 0, stream>>>(ei, deg);
    k_scan2<<<1, 1024, 0, stream>>>(deg, offs);
    hipMemcpyAsync(cursor, offs, (size_t)N_NODES * 4, hipMemcpyDeviceToDevice, stream);
    k_scatter<<<(ET_EDGES + 255) / 256, 256, 0, stream>>>(ei, cursor, csrsrc);
    k_gbounds<<<(N_NODES + 255) / 256, 256, 0, stream>>>(batch, gstart);

    const float* xin = x;
    const float* bns = nullptr;   // BN scale/shift applied to mgemm input (fused)
    const float* bnh = nullptr;
    for (int l = 0; l < 3; ++l) {
        int K = (l == 0) ? F_IN : DM;
        const float* W   = (const float*)d_in[3 + 6 * l];
        const float* as_ = (const float*)d_in[4 + 6 * l];
        const float* ad_ = (const float*)d_in[5 + 6 * l];
        const float* bia = (const float*)d_in[6 + 6 * l];
        const float* gam = (const float*)d_in[7 + 6 * l];
        const float* bet = (const float*)d_in[8 + 6 * l];

        k_wprep<<<(K * DM + 255) / 256, 256, 0, stream>>>(W, Wh, Wl, K);
        k_mgemm<<<dim3(4, (N_NODES + 127) / 128), 256, 0, stream>>>(
            xin, Wh, Wl, bns, bnh, as_, ad_, Hb, ssrc, sdst, N_NODES, K);
        k_aggregate<<<(N_NODES + 3) / 4, 256, 0, stream>>>(Hb, ssrc, sdst, offs, csrsrc, bia, A);
        hipMemsetAsync(bnstat, 0, 1024 * 4, stream);
        k_bnstats<<<(N_NODES + BN_ROWS - 1) / BN_ROWS, 256, 0, stream>>>(A, bnstat);
        k_bnfin<<<2, 256, 0, stream>>>(bnstat, gam, bet, bnscale, bnshift);
        xin = A; bns = bnscale; bnh = bnshift;
    }
    k_pool<<<G_GRAPHS, 64, 0, stream>>>(A, gstart, bnscale, bnshift, pool);
    k_mlp<<<G_GRAPHS, 128, 0, stream>>>(pool, c1w, c1b, c2w, c2b, c3w, c3b,
                                        (float*)d_out);
}